// Round 3
// baseline (723.232 us; speedup 1.0000x reference)
//
#include <hip/hip_runtime.h>
#include <hip/hip_bf16.h>
#include <stdint.h>

// LearnableCorrBlock: fmap1/2 [2,256,64,64] f32, coords [2,2,64,64], raw_P [256,256], raw_D [256]
// out [2, 4*81, 64, 64] f32.
//
// Strategy:
//  - W-metric chain: S from raw_P; inv(I-S) via Neumann squaring product (terms to S^15);
//    P = (I+S)inv(I-S); Wms = P^T diag(dvec) P / 16.
//  - g1[b,i,c] = sum_c' f1[b,c',i] * Wms[c',c]   (stored bf16)
//  - t_l[b,y,x,c] = avg-pooled fmap2, channel-contiguous, bf16, levels 0..3
//  - sampler: per query, per level: 10x10 grid of 256-dots (bf16 inputs, f32 accum),
//    then bilinear scalar combine into 81 outputs per level.

#define DIM 256
#define HH 64
#define WW 64
#define HW 4096
#define NB 2
#define NQ 8192
#define NCH 324

__device__ __constant__ size_t c_toff[4] = {0, 2097152, 2621440, 2752512};

static __device__ __forceinline__ unsigned short f2bf(float f) {
    unsigned int u = __float_as_uint(f);
    unsigned int r = (u + 0x7fffu + ((u >> 16) & 1u)) >> 16;   // RNE
    return (unsigned short)r;
}

// ---------- 1. prep: skew S and diagonal dvec ----------
__global__ void prep_kernel(const float* __restrict__ rp, const float* __restrict__ rd,
                            float* __restrict__ S, float* __restrict__ dvec) {
    int i = blockIdx.x, j = threadIdx.x;
    float v = 0.f;
    if (j > i)      v =  0.5f * rp[i * DIM + j];
    else if (j < i) v = -0.5f * rp[j * DIM + i];
    S[i * DIM + j] = v;
    if (i == 0) {
        float t = atanf(rd[j]) * 0.63661977236758134f;  // 2/pi
        dvec[j] = (1.0f + t) / (1.0f - t);
    }
}

// ---------- 2. small 256x256 GEMM: C = (A + aI*I) @ (B + bI*I) ----------
__global__ void gemm256_kernel(const float* __restrict__ A, const float* __restrict__ B,
                               float* __restrict__ C, int aI, int bI) {
    int i0 = blockIdx.x * 4;
    int j = threadIdx.x;
    float acc0 = 0.f, acc1 = 0.f, acc2 = 0.f, acc3 = 0.f;
    for (int k = 0; k < DIM; ++k) {
        float b = B[k * DIM + j] + ((bI && k == j) ? 1.f : 0.f);
        float a0 = A[(i0 + 0) * DIM + k] + ((aI && (i0 + 0) == k) ? 1.f : 0.f);
        float a1 = A[(i0 + 1) * DIM + k] + ((aI && (i0 + 1) == k) ? 1.f : 0.f);
        float a2 = A[(i0 + 2) * DIM + k] + ((aI && (i0 + 2) == k) ? 1.f : 0.f);
        float a3 = A[(i0 + 3) * DIM + k] + ((aI && (i0 + 3) == k) ? 1.f : 0.f);
        acc0 += a0 * b; acc1 += a1 * b; acc2 += a2 * b; acc3 += a3 * b;
    }
    C[(i0 + 0) * DIM + j] = acc0;
    C[(i0 + 1) * DIM + j] = acc1;
    C[(i0 + 2) * DIM + j] = acc2;
    C[(i0 + 3) * DIM + j] = acc3;
}

// ---------- 3. Wms[i,j] = sum_k P[k,i]*dvec[k]*P[k,j] / 16 ----------
__global__ void gemmW_kernel(const float* __restrict__ P, const float* __restrict__ dvec,
                             float* __restrict__ Wms) {
    int i = blockIdx.x, j = threadIdx.x;
    float acc = 0.f;
    for (int k = 0; k < DIM; ++k)
        acc += P[k * DIM + i] * dvec[k] * P[k * DIM + j];
    Wms[i * DIM + j] = acc * 0.0625f;
}

// ---------- 4. g1[b,i,c] = sum_c' f1[b,c',i] * Wms[c',c]  (bf16 out) ----------
__global__ __launch_bounds__(256) void g1_kernel(const float* __restrict__ f1,
                                                 const float* __restrict__ Wms,
                                                 unsigned int* __restrict__ g1u) {
    int b = blockIdx.z;
    int i = blockIdx.x * 64 + (threadIdx.x & 63);
    int cb = blockIdx.y * 128 + (threadIdx.x >> 6) * 32;
    const float* f1p = f1 + (size_t)b * DIM * HW + i;
    float acc[32];
#pragma unroll
    for (int c = 0; c < 32; ++c) acc[c] = 0.f;
    for (int cp = 0; cp < DIM; ++cp) {
        float a = f1p[(size_t)cp * HW];
        const float* wrow = Wms + cp * DIM + cb;  // wave-uniform -> scalar loads
#pragma unroll
        for (int c = 0; c < 32; ++c) acc[c] += a * wrow[c];
    }
    unsigned int* out = g1u + (((size_t)b * HW + i) * DIM + cb) / 2;
#pragma unroll
    for (int m = 0; m < 16; ++m) {
        unsigned int u = (unsigned int)f2bf(acc[2 * m]) | ((unsigned int)f2bf(acc[2 * m + 1]) << 16);
        out[m] = u;
    }
}

// ---------- 5. pooled + transposed f2 -> t_l[b,y,x,c] bf16 ----------
__global__ void pool_kernel(const float* __restrict__ f2, unsigned short* __restrict__ t) {
    int b = blockIdx.y;
    int r = blockIdx.x;
    int lvl, y;
    if (r < 64)       { lvl = 0; y = r; }
    else if (r < 96)  { lvl = 1; y = r - 64; }
    else if (r < 112) { lvl = 2; y = r - 96; }
    else              { lvl = 3; y = r - 112; }
    int wl = 64 >> lvl;
    int s = 1 << lvl;
    float inv = 1.0f / (float)(s * s);
    int c = threadIdx.x;
    const float* src = f2 + ((size_t)b * DIM + c) * HW;
    unsigned short* dst = t + c_toff[lvl] + (((size_t)b * wl + y) * (size_t)wl) * DIM + c;
    for (int x = 0; x < wl; ++x) {
        float acc = 0.f;
        for (int dy = 0; dy < s; ++dy)
            for (int dx = 0; dx < s; ++dx)
                acc += src[(y * s + dy) * WW + (x * s + dx)];
        dst[(size_t)x * DIM] = f2bf(acc * inv);
    }
}

// ---------- 6. sampler ----------
__global__ __launch_bounds__(256) void sample_kernel(const unsigned short* __restrict__ g1,
                                                     const unsigned short* __restrict__ t,
                                                     const float* __restrict__ coords,
                                                     float* __restrict__ out) {
    __shared__ float gf[DIM];
    __shared__ float Dl[4][10][10];
    int bid = blockIdx.x;
    int q = (bid & 7) * 1024 + (bid >> 3);   // bijective XCD swizzle (8192 % 8 == 0)
    int b = q >> 12, y = (q >> 6) & 63, x = q & 63;
    int tid = threadIdx.x;

    {   // g1[q,:] -> LDS as f32
        unsigned short u = g1[(size_t)q * DIM + tid];
        gf[tid] = __uint_as_float(((unsigned int)u) << 16);
    }
    float cx = coords[(((size_t)b * 2 + 0) * HH + y) * WW + x];
    float cy = coords[(((size_t)b * 2 + 1) * HH + y) * WW + x];
    __syncthreads();

    // phase 1: 400 dots (4 levels x 10x10 integer grid)
    for (int d = tid; d < 400; d += 256) {
        int lvl = d / 100, p = d % 100;
        int u = p / 10, v = p % 10;
        float scale = 1.0f / (float)(1 << lvl);
        float cxl = cx * scale, cyl = cy * scale;
        int X0 = (int)floorf(cxl), Y0 = (int)floorf(cyl);
        int wl = 64 >> lvl;
        int xi = X0 - 4 + u, yi = Y0 - 4 + v;
        float acc = 0.f;
        if (xi >= 0 && xi < wl && yi >= 0 && yi < wl) {
            const uint4* tv = (const uint4*)(t + c_toff[lvl] + (((size_t)b * wl + yi) * (size_t)wl + xi) * DIM);
#pragma unroll
            for (int k = 0; k < 32; ++k) {
                uint4 w = tv[k];
                const float* gp = &gf[k * 8];
                acc += __uint_as_float(w.x << 16)          * gp[0];
                acc += __uint_as_float(w.x & 0xffff0000u)  * gp[1];
                acc += __uint_as_float(w.y << 16)          * gp[2];
                acc += __uint_as_float(w.y & 0xffff0000u)  * gp[3];
                acc += __uint_as_float(w.z << 16)          * gp[4];
                acc += __uint_as_float(w.z & 0xffff0000u)  * gp[5];
                acc += __uint_as_float(w.w << 16)          * gp[6];
                acc += __uint_as_float(w.w & 0xffff0000u)  * gp[7];
            }
        }
        Dl[lvl][u][v] = acc;
    }
    __syncthreads();

    // phase 2: bilinear combine -> 324 channels
    for (int ch = tid; ch < NCH; ch += 256) {
        int lvl = ch / 81, rem = ch % 81;
        int a = rem / 9, bb = rem % 9;
        float scale = 1.0f / (float)(1 << lvl);
        float cxl = cx * scale, cyl = cy * scale;
        float fx = cxl - floorf(cxl), fy = cyl - floorf(cyl);
        float wx0 = 1.f - fx, wy0 = 1.f - fy;
        float v00 = Dl[lvl][a][bb],     v10 = Dl[lvl][a + 1][bb];
        float v01 = Dl[lvl][a][bb + 1], v11 = Dl[lvl][a + 1][bb + 1];
        float val = wy0 * (wx0 * v00 + fx * v10) + fy * (wx0 * v01 + fx * v11);
        out[(((size_t)b * NCH + ch) * HH + y) * WW + x] = val;
    }
}

extern "C" void kernel_launch(void* const* d_in, const int* in_sizes, int n_in,
                              void* d_out, int out_size, void* d_ws, size_t ws_size,
                              hipStream_t stream) {
    const float* f1     = (const float*)d_in[0];
    const float* f2     = (const float*)d_in[1];
    const float* coords = (const float*)d_in[2];
    const float* rp     = (const float*)d_in[3];
    const float* rd     = (const float*)d_in[4];
    float* out = (float*)d_out;

    // workspace carve (floats)
    float* S    = (float*)d_ws;
    float* M2   = S   + 65536;
    float* M4   = M2  + 65536;
    float* M8   = M4  + 65536;
    float* Rb1  = M8  + 65536;
    float* Rb2  = Rb1 + 65536;
    float* Rb3  = Rb2 + 65536;
    float* Pm   = Rb3 + 65536;
    float* Wms  = Pm  + 65536;
    float* dvec = Wms + 65536;                       // 256 floats
    unsigned short* g1 = (unsigned short*)(dvec + 256);      // 2*4096*256 bf16
    unsigned short* t  = g1 + (size_t)NB * HW * DIM;         // 2785280 bf16

    prep_kernel<<<256, 256, 0, stream>>>(rp, rd, S, dvec);
    gemm256_kernel<<<64, 256, 0, stream>>>(S,   S,   M2,  0, 0);   // S^2
    gemm256_kernel<<<64, 256, 0, stream>>>(M2,  M2,  M4,  0, 0);   // S^4
    gemm256_kernel<<<64, 256, 0, stream>>>(M4,  M4,  M8,  0, 0);   // S^8
    gemm256_kernel<<<64, 256, 0, stream>>>(S,   M2,  Rb1, 1, 1);   // (I+S)(I+S^2)
    gemm256_kernel<<<64, 256, 0, stream>>>(Rb1, M4,  Rb2, 0, 1);   // *(I+S^4)
    gemm256_kernel<<<64, 256, 0, stream>>>(Rb2, M8,  Rb3, 0, 1);   // *(I+S^8) = inv(I-S)
    gemm256_kernel<<<64, 256, 0, stream>>>(S,   Rb3, Pm,  1, 0);   // P = (I+S) inv(I-S)
    gemmW_kernel<<<256, 256, 0, stream>>>(Pm, dvec, Wms);

    g1_kernel<<<dim3(64, 2, 2), 256, 0, stream>>>(f1, Wms, (unsigned int*)g1);
    pool_kernel<<<dim3(120, 2), 256, 0, stream>>>(f2, t);
    sample_kernel<<<NQ, 256, 0, stream>>>(g1, t, coords, out);
}

// Round 5
// 540.215 us; speedup vs baseline: 1.3388x; 1.3388x over previous
//
#include <hip/hip_runtime.h>
#include <hip/hip_bf16.h>
#include <stdint.h>

// LearnableCorrBlock: fmap1/2 [2,256,64,64] f32, coords [2,2,64,64], raw_P [256,256], raw_D [256]
// out [2, 4*81, 64, 64] f32.
//
//  - W-chain: P = (I+S)^2 (I+S^2)(I+S^4)  (Neumann, err ~||S||^8 ~ 4e-7); Wms = P^T D P /16
//  - g1[b,i,c] = f1^T Wms (bf16), coalesced via LDS transpose
//  - t_l[b,y,x,c] = pooled fmap2, channel-contiguous bf16
//  - sampler: 8 queries/block, p-major dot ordering (8-way load merge), 8-acc ILP

#define DIM 256
#define HH 64
#define WW 64
#define HW 4096
#define NB 2
#define NQ 8192
#define NCH 324
#define QB 8

__device__ __constant__ size_t c_toff[4] = {0, 2097152, 2621440, 2752512};

static __device__ __forceinline__ unsigned short f2bf(float f) {
    unsigned int u = __float_as_uint(f);
    unsigned int r = (u + 0x7fffu + ((u >> 16) & 1u)) >> 16;   // RNE
    return (unsigned short)r;
}
static __device__ __forceinline__ float bflo(unsigned int u) { return __uint_as_float(u << 16); }
static __device__ __forceinline__ float bfhi(unsigned int u) { return __uint_as_float(u & 0xffff0000u); }

// ---------- 1. prep: skew S and diagonal dvec ----------
__global__ void prep_kernel(const float* __restrict__ rp, const float* __restrict__ rd,
                            float* __restrict__ S, float* __restrict__ dvec) {
    int i = blockIdx.x, j = threadIdx.x;
    float v = 0.f;
    if (j > i)      v =  0.5f * rp[i * DIM + j];
    else if (j < i) v = -0.5f * rp[j * DIM + i];
    S[i * DIM + j] = v;
    if (i == 0) {
        float t = atanf(rd[j]) * 0.63661977236758134f;  // 2/pi
        dvec[j] = (1.0f + t) / (1.0f - t);
    }
}

// ---------- 2. row-per-block GEMMs (A-row uniform -> s_loads; B coalesced) ----------
__global__ __launch_bounds__(256) void gemm_plain(const float* __restrict__ A,
                                                  const float* __restrict__ B,
                                                  float* __restrict__ C) {
    int i = blockIdx.x, j = threadIdx.x;
    const float* a = A + (size_t)i * DIM;
    float acc = 0.f;
#pragma unroll 8
    for (int k = 0; k < DIM; ++k) acc += a[k] * B[k * DIM + j];
    C[i * DIM + j] = acc;
}

// U = (I + 2S + M2) @ (I + M2)  ==  (I+2S+M2)@M2 + (I+2S+M2)
__global__ __launch_bounds__(256) void gemm_U(const float* __restrict__ S,
                                              const float* __restrict__ M2,
                                              float* __restrict__ U) {
    int i = blockIdx.x, j = threadIdx.x;
    const float* s = S + (size_t)i * DIM;
    const float* m = M2 + (size_t)i * DIM;
    float acc = 0.f;
#pragma unroll 8
    for (int k = 0; k < DIM; ++k) {
        float av = 2.f * s[k] + m[k] + ((k == i) ? 1.f : 0.f);
        acc += av * M2[k * DIM + j];
    }
    acc += 2.f * s[j] + m[j] + ((j == i) ? 1.f : 0.f);
    U[i * DIM + j] = acc;
}

// P = U @ (I + M4) == U@M4 + U
__global__ __launch_bounds__(256) void gemm_P(const float* __restrict__ U,
                                              const float* __restrict__ M4,
                                              float* __restrict__ P) {
    int i = blockIdx.x, j = threadIdx.x;
    const float* a = U + (size_t)i * DIM;
    float acc = 0.f;
#pragma unroll 8
    for (int k = 0; k < DIM; ++k) acc += a[k] * M4[k * DIM + j];
    acc += a[j];
    P[i * DIM + j] = acc;
}

// ---------- 3. Wms[i,j] = sum_k P[k,i]*d[k]*P[k,j] / 16 (LDS-staged column) ----------
__global__ __launch_bounds__(256) void gemmW_kernel(const float* __restrict__ P,
                                                    const float* __restrict__ dvec,
                                                    float* __restrict__ Wms) {
    __shared__ float col[DIM];
    int i = blockIdx.x, j = threadIdx.x;
    col[j] = P[j * DIM + i] * dvec[j];
    __syncthreads();
    float acc = 0.f;
#pragma unroll 8
    for (int k = 0; k < DIM; ++k) acc += col[k] * P[k * DIM + j];
    Wms[i * DIM + j] = acc * 0.0625f;
}

// ---------- 4. g1[b,i,c] = sum_c' f1[b,c',i] * Wms[c',c]  (bf16, coalesced store) ----------
__global__ __launch_bounds__(256) void g1_kernel(const float* __restrict__ f1,
                                                 const float* __restrict__ Wms,
                                                 unsigned int* __restrict__ g1u) {
    __shared__ unsigned int lt[64][65];
    int b = blockIdx.z;
    int tid = threadIdx.x;
    int il = tid & 63, w = tid >> 6;
    int i = blockIdx.x * 64 + il;
    int cb = blockIdx.y * 128 + w * 32;
    const float* f1p = f1 + (size_t)b * DIM * HW + i;
    float acc[32];
#pragma unroll
    for (int c = 0; c < 32; ++c) acc[c] = 0.f;
    for (int cp = 0; cp < DIM; ++cp) {
        float a = f1p[(size_t)cp * HW];
        const float* wrow = Wms + cp * DIM + cb;  // wave-uniform -> scalar loads
#pragma unroll
        for (int c = 0; c < 32; ++c) acc[c] += a * wrow[c];
    }
#pragma unroll
    for (int m = 0; m < 16; ++m) {
        unsigned int u = (unsigned int)f2bf(acc[2 * m]) | ((unsigned int)f2bf(acc[2 * m + 1]) << 16);
        lt[il][w * 16 + m] = u;
    }
    __syncthreads();
    unsigned int* dst = g1u + ((size_t)b * HW + blockIdx.x * 64) * 128 + blockIdx.y * 64;
#pragma unroll
    for (int j2 = 0; j2 < 16; ++j2) {
        int idx = tid + 256 * j2;
        int row = idx >> 6, cu = idx & 63;
        dst[(size_t)row * 128 + cu] = lt[row][cu];
    }
}

// ---------- 5. pooled + transposed f2 -> t_l[b,y,x,c] bf16 ----------
__global__ void pool_kernel(const float* __restrict__ f2, unsigned short* __restrict__ t) {
    int b = blockIdx.y;
    int r = blockIdx.x;
    int lvl, y;
    if (r < 64)       { lvl = 0; y = r; }
    else if (r < 96)  { lvl = 1; y = r - 64; }
    else if (r < 112) { lvl = 2; y = r - 96; }
    else              { lvl = 3; y = r - 112; }
    int wl = 64 >> lvl;
    int s = 1 << lvl;
    float inv = 1.0f / (float)(s * s);
    int c = threadIdx.x;
    const float* src = f2 + ((size_t)b * DIM + c) * HW;
    unsigned short* dst = t + c_toff[lvl] + (((size_t)b * wl + y) * (size_t)wl) * DIM + c;
    for (int x = 0; x < wl; ++x) {
        float acc = 0.f;
        for (int dy = 0; dy < s; ++dy)
            for (int dx = 0; dx < s; ++dx)
                acc += src[(y * s + dy) * WW + (x * s + dx)];
        dst[(size_t)x * DIM] = f2bf(acc * inv);
    }
}

// ---------- 6. sampler v2: 8 queries/block, p-major, 8 accumulators ----------
__global__ __launch_bounds__(256, 4) void sample_kernel(const unsigned short* __restrict__ g1,
                                                        const unsigned short* __restrict__ t,
                                                        const float* __restrict__ coords,
                                                        float* __restrict__ out) {
    __shared__ float gf[QB][260];     // 260-stride: bank(4q+e) tiles 0..31 for b128 reads
    __shared__ float Dl[QB][401];     // 401-stride: 17q%32 distinct banks
    __shared__ float cxs[QB], cys[QB];

    int bid = blockIdx.x;
    int swz = (bid & 7) * 128 + (bid >> 3);   // bijective XCD swizzle, 1024 blocks
    int qbase = swz * QB;
    int b = qbase >> 12, y = (qbase >> 6) & 63, x0 = qbase & 63;
    int tid = threadIdx.x;

    {   // 8 g1 rows (2048 bf16 = 256 uint4), one uint4 per thread, unpack to f32 LDS
        const uint4* src = (const uint4*)(g1 + (size_t)qbase * DIM);
        uint4 wv = src[tid];
        float* dst = &gf[tid >> 5][(tid & 31) * 8];
        dst[0] = bflo(wv.x); dst[1] = bfhi(wv.x);
        dst[2] = bflo(wv.y); dst[3] = bfhi(wv.y);
        dst[4] = bflo(wv.z); dst[5] = bfhi(wv.z);
        dst[6] = bflo(wv.w); dst[7] = bfhi(wv.w);
    }
    if (tid < QB) {
        cxs[tid] = coords[(((size_t)b * 2 + 0) * HH + y) * WW + (x0 + tid)];
        cys[tid] = coords[(((size_t)b * 2 + 1) * HH + y) * WW + (x0 + tid)];
    }
    __syncthreads();

    int q = tid & (QB - 1);
    float cx = cxs[q], cy = cys[q];

    // phase 1: QB*400 = 3200 dots; idx = p*8 + q
    for (int it = 0; it < 13; ++it) {
        int idx = tid + it * 256;
        if (idx < QB * 400) {
            int p = idx >> 3;                 // 0..399
            int lvl = p / 100, rem = p % 100;
            int u = rem / 10, v = rem % 10;
            float scale = 1.0f / (float)(1 << lvl);
            float cxl = cx * scale, cyl = cy * scale;
            int X0 = (int)floorf(cxl), Y0 = (int)floorf(cyl);
            int wl = 64 >> lvl;
            int xi = X0 - 4 + u, yi = Y0 - 4 + v;
            float r = 0.f;
            if (xi >= 0 && xi < wl && yi >= 0 && yi < wl) {
                const uint4* tv = (const uint4*)(t + c_toff[lvl] + (((size_t)b * wl + yi) * (size_t)wl + xi) * DIM);
                float a0 = 0.f, a1 = 0.f, a2 = 0.f, a3 = 0.f, a4 = 0.f, a5 = 0.f, a6 = 0.f, a7 = 0.f;
#pragma unroll
                for (int k = 0; k < 32; ++k) {
                    uint4 wv = tv[k];
                    float4 ga = *(const float4*)&gf[q][k * 8];
                    float4 gb = *(const float4*)&gf[q][k * 8 + 4];
                    a0 += bflo(wv.x) * ga.x;  a1 += bfhi(wv.x) * ga.y;
                    a2 += bflo(wv.y) * ga.z;  a3 += bfhi(wv.y) * ga.w;
                    a4 += bflo(wv.z) * gb.x;  a5 += bfhi(wv.z) * gb.y;
                    a6 += bflo(wv.w) * gb.z;  a7 += bfhi(wv.w) * gb.w;
                }
                r = ((a0 + a1) + (a2 + a3)) + ((a4 + a5) + (a6 + a7));
            }
            Dl[q][p] = r;
        }
    }
    __syncthreads();

    // phase 2: QB*324 outputs; idx = ch*8 + q
    for (int idx = tid; idx < QB * NCH; idx += 256) {
        int ch = idx >> 3, qq = idx & (QB - 1);
        int lvl = ch / 81, rem2 = ch % 81;
        int a = rem2 / 9, bb = rem2 % 9;
        float cx2 = cxs[qq], cy2 = cys[qq];
        float scale = 1.0f / (float)(1 << lvl);
        float cxl = cx2 * scale, cyl = cy2 * scale;
        float fx = cxl - floorf(cxl), fy = cyl - floorf(cyl);
        float wx0 = 1.f - fx, wy0 = 1.f - fy;
        int base = lvl * 100 + a * 10 + bb;
        float v00 = Dl[qq][base],     v10 = Dl[qq][base + 10];
        float v01 = Dl[qq][base + 1], v11 = Dl[qq][base + 11];
        float val = wy0 * (wx0 * v00 + fx * v10) + fy * (wx0 * v01 + fx * v11);
        out[(((size_t)b * NCH + ch) * HH + y) * WW + (x0 + qq)] = val;
    }
}

extern "C" void kernel_launch(void* const* d_in, const int* in_sizes, int n_in,
                              void* d_out, int out_size, void* d_ws, size_t ws_size,
                              hipStream_t stream) {
    const float* f1     = (const float*)d_in[0];
    const float* f2     = (const float*)d_in[1];
    const float* coords = (const float*)d_in[2];
    const float* rp     = (const float*)d_in[3];
    const float* rd     = (const float*)d_in[4];
    float* out = (float*)d_out;

    // workspace carve (floats)
    float* S    = (float*)d_ws;
    float* M2   = S   + 65536;
    float* M4   = M2  + 65536;
    float* Um   = M4  + 65536;
    float* Pm   = Um  + 65536;
    float* Wms  = Pm  + 65536;
    float* dvec = Wms + 65536;                               // 256 floats
    unsigned short* g1 = (unsigned short*)(dvec + 256);      // 2*4096*256 bf16
    unsigned short* t  = g1 + (size_t)NB * HW * DIM;         // 2785280 bf16

    prep_kernel<<<256, 256, 0, stream>>>(rp, rd, S, dvec);
    gemm_plain<<<256, 256, 0, stream>>>(S,  S,  M2);     // S^2
    gemm_plain<<<256, 256, 0, stream>>>(M2, M2, M4);     // S^4
    gemm_U    <<<256, 256, 0, stream>>>(S,  M2, Um);     // (I+S)^2 (I+S^2)
    gemm_P    <<<256, 256, 0, stream>>>(Um, M4, Pm);     // * (I+S^4) = P
    gemmW_kernel<<<256, 256, 0, stream>>>(Pm, dvec, Wms);

    g1_kernel<<<dim3(64, 2, 2), 256, 0, stream>>>(f1, Wms, (unsigned int*)g1);
    pool_kernel<<<dim3(120, 2), 256, 0, stream>>>(f2, t);
    sample_kernel<<<NQ / QB, 256, 0, stream>>>(g1, t, coords, out);
}

// Round 8
// 465.633 us; speedup vs baseline: 1.5532x; 1.1602x over previous
//
#include <hip/hip_runtime.h>
#include <hip/hip_bf16.h>
#include <stdint.h>

// LearnableCorrBlock: fmap1/2 [2,256,64,64] f32, coords [2,2,64,64], raw_P [256,256], raw_D [256]
// out [2, 4*81, 64, 64] f32.
//
//  - W-chain: P = (I+S)^2 (I+S^2)(I+S^4)  (Neumann, err ~||S||^8 ~ 4e-7); Wms = P^T D P /16
//  - g1[b,i,c] = f1^T Wms (bf16), coalesced via LDS transpose
//  - t_l[b,y,x,c] = pooled fmap2, channel-contiguous bf16
//  - sampler: 8 queries/block, p-major dot ordering (8-way load merge), packed-bf16 LDS + v_dot2
//    NOTE: no min-waves launch_bounds hint — (256,4) forced 64 VGPRs and ~217MB/dispatch of
//    scratch spill traffic (round 5 counters: WRITE_SIZE 228MB vs 10.6MB ideal).

#define DIM 256
#define HH 64
#define WW 64
#define HW 4096
#define NB 2
#define NQ 8192
#define NCH 324
#define QB 8

__device__ __constant__ size_t c_toff[4] = {0, 2097152, 2621440, 2752512};

static __device__ __forceinline__ unsigned short f2bf(float f) {
    unsigned int u = __float_as_uint(f);
    unsigned int r = (u + 0x7fffu + ((u >> 16) & 1u)) >> 16;   // RNE
    return (unsigned short)r;
}
static __device__ __forceinline__ float bflo(unsigned int u) { return __uint_as_float(u << 16); }
static __device__ __forceinline__ float bfhi(unsigned int u) { return __uint_as_float(u & 0xffff0000u); }

#if __has_builtin(__builtin_amdgcn_fdot2_f32_bf16)
typedef __bf16 bf16x2_t __attribute__((ext_vector_type(2)));
#define HAVE_DOT2 1
static __device__ __forceinline__ float dot2bf(unsigned int a, unsigned int b, float c) {
    return __builtin_amdgcn_fdot2_f32_bf16(__builtin_bit_cast(bf16x2_t, a),
                                           __builtin_bit_cast(bf16x2_t, b), c, false);
}
#else
#define HAVE_DOT2 0
#endif

// ---------- 1. prep: skew S and diagonal dvec ----------
__global__ void prep_kernel(const float* __restrict__ rp, const float* __restrict__ rd,
                            float* __restrict__ S, float* __restrict__ dvec) {
    int i = blockIdx.x, j = threadIdx.x;
    float v = 0.f;
    if (j > i)      v =  0.5f * rp[i * DIM + j];
    else if (j < i) v = -0.5f * rp[j * DIM + i];
    S[i * DIM + j] = v;
    if (i == 0) {
        float t = atanf(rd[j]) * 0.63661977236758134f;  // 2/pi
        dvec[j] = (1.0f + t) / (1.0f - t);
    }
}

// ---------- 2. row-per-block GEMMs (A-row uniform -> s_loads; B coalesced) ----------
__global__ __launch_bounds__(256) void gemm_plain(const float* __restrict__ A,
                                                  const float* __restrict__ B,
                                                  float* __restrict__ C) {
    int i = blockIdx.x, j = threadIdx.x;
    const float* a = A + (size_t)i * DIM;
    float acc = 0.f;
#pragma unroll 8
    for (int k = 0; k < DIM; ++k) acc += a[k] * B[k * DIM + j];
    C[i * DIM + j] = acc;
}

// U = (I + 2S + M2) @ (I + M2)
__global__ __launch_bounds__(256) void gemm_U(const float* __restrict__ S,
                                              const float* __restrict__ M2,
                                              float* __restrict__ U) {
    int i = blockIdx.x, j = threadIdx.x;
    const float* s = S + (size_t)i * DIM;
    const float* m = M2 + (size_t)i * DIM;
    float acc = 0.f;
#pragma unroll 8
    for (int k = 0; k < DIM; ++k) {
        float av = 2.f * s[k] + m[k] + ((k == i) ? 1.f : 0.f);
        acc += av * M2[k * DIM + j];
    }
    acc += 2.f * s[j] + m[j] + ((j == i) ? 1.f : 0.f);
    U[i * DIM + j] = acc;
}

// P = U @ (I + M4)
__global__ __launch_bounds__(256) void gemm_P(const float* __restrict__ U,
                                              const float* __restrict__ M4,
                                              float* __restrict__ P) {
    int i = blockIdx.x, j = threadIdx.x;
    const float* a = U + (size_t)i * DIM;
    float acc = 0.f;
#pragma unroll 8
    for (int k = 0; k < DIM; ++k) acc += a[k] * M4[k * DIM + j];
    acc += a[j];
    P[i * DIM + j] = acc;
}

// ---------- 3. Wms[i,j] = sum_k P[k,i]*d[k]*P[k,j] / 16 (LDS-staged column) ----------
__global__ __launch_bounds__(256) void gemmW_kernel(const float* __restrict__ P,
                                                    const float* __restrict__ dvec,
                                                    float* __restrict__ Wms) {
    __shared__ float col[DIM];
    int i = blockIdx.x, j = threadIdx.x;
    col[j] = P[j * DIM + i] * dvec[j];
    __syncthreads();
    float acc = 0.f;
#pragma unroll 8
    for (int k = 0; k < DIM; ++k) acc += col[k] * P[k * DIM + j];
    Wms[i * DIM + j] = acc * 0.0625f;
}

// ---------- 4. g1[b,i,c] = sum_c' f1[b,c',i] * Wms[c',c]  (bf16, coalesced store) ----------
__global__ __launch_bounds__(256) void g1_kernel(const float* __restrict__ f1,
                                                 const float* __restrict__ Wms,
                                                 unsigned int* __restrict__ g1u) {
    __shared__ unsigned int lt[64][65];
    int b = blockIdx.z;
    int tid = threadIdx.x;
    int il = tid & 63, w = tid >> 6;
    int i = blockIdx.x * 64 + il;
    int cb = blockIdx.y * 128 + w * 32;
    const float* f1p = f1 + (size_t)b * DIM * HW + i;
    float acc[32];
#pragma unroll
    for (int c = 0; c < 32; ++c) acc[c] = 0.f;
    for (int cp = 0; cp < DIM; ++cp) {
        float a = f1p[(size_t)cp * HW];
        const float* wrow = Wms + cp * DIM + cb;  // wave-uniform -> scalar loads
#pragma unroll
        for (int c = 0; c < 32; ++c) acc[c] += a * wrow[c];
    }
#pragma unroll
    for (int m = 0; m < 16; ++m) {
        unsigned int u = (unsigned int)f2bf(acc[2 * m]) | ((unsigned int)f2bf(acc[2 * m + 1]) << 16);
        lt[il][w * 16 + m] = u;
    }
    __syncthreads();
    unsigned int* dst = g1u + ((size_t)b * HW + blockIdx.x * 64) * 128 + blockIdx.y * 64;
#pragma unroll
    for (int j2 = 0; j2 < 16; ++j2) {
        int idx = tid + 256 * j2;
        int row = idx >> 6, cu = idx & 63;
        dst[(size_t)row * 128 + cu] = lt[row][cu];
    }
}

// ---------- 5. pooled + transposed f2 -> t_l[b,y,x,c] bf16 ----------
__global__ void pool_kernel(const float* __restrict__ f2, unsigned short* __restrict__ t) {
    int b = blockIdx.y;
    int r = blockIdx.x;
    int lvl, y;
    if (r < 64)       { lvl = 0; y = r; }
    else if (r < 96)  { lvl = 1; y = r - 64; }
    else if (r < 112) { lvl = 2; y = r - 96; }
    else              { lvl = 3; y = r - 112; }
    int wl = 64 >> lvl;
    int s = 1 << lvl;
    float inv = 1.0f / (float)(s * s);
    int c = threadIdx.x;
    const float* src = f2 + ((size_t)b * DIM + c) * HW;
    unsigned short* dst = t + c_toff[lvl] + (((size_t)b * wl + y) * (size_t)wl) * DIM + c;
    for (int x = 0; x < wl; ++x) {
        float acc = 0.f;
        for (int dy = 0; dy < s; ++dy)
            for (int dx = 0; dx < s; ++dx)
                acc += src[(y * s + dy) * WW + (x * s + dx)];
        dst[(size_t)x * DIM] = f2bf(acc * inv);
    }
}

// ---------- 6. sampler v3: 8 queries/block, p-major, packed-bf16 LDS + dot2 ----------
__global__ __launch_bounds__(256) void sample_kernel(const unsigned short* __restrict__ g1,
                                                     const unsigned short* __restrict__ t,
                                                     const float* __restrict__ coords,
                                                     float* __restrict__ out) {
#if HAVE_DOT2
    __shared__ __align__(16) unsigned int gu[QB][132];  // packed bf16 pairs; 528B row stride (16B multiple)
#else
    __shared__ __align__(16) float gf[QB][260];
#endif
    __shared__ float Dl[QB][401];
    __shared__ float cxs[QB], cys[QB];

    int bid = blockIdx.x;
    int swz = (bid & 7) * 128 + (bid >> 3);   // bijective XCD swizzle, 1024 blocks
    int qbase = swz * QB;
    int b = qbase >> 12, y = (qbase >> 6) & 63, x0 = qbase & 63;
    int tid = threadIdx.x;

    {   // 8 g1 rows (2048 bf16 = 256 uint4), one uint4 per thread
        const uint4* src = (const uint4*)(g1 + (size_t)qbase * DIM);
        uint4 wv = src[tid];
#if HAVE_DOT2
        *(uint4*)&gu[tid >> 5][(tid & 31) * 4] = wv;
#else
        float* dst = &gf[tid >> 5][(tid & 31) * 8];
        dst[0] = bflo(wv.x); dst[1] = bfhi(wv.x);
        dst[2] = bflo(wv.y); dst[3] = bfhi(wv.y);
        dst[4] = bflo(wv.z); dst[5] = bfhi(wv.z);
        dst[6] = bflo(wv.w); dst[7] = bfhi(wv.w);
#endif
    }
    if (tid < QB) {
        cxs[tid] = coords[(((size_t)b * 2 + 0) * HH + y) * WW + (x0 + tid)];
        cys[tid] = coords[(((size_t)b * 2 + 1) * HH + y) * WW + (x0 + tid)];
    }
    __syncthreads();

    int q = tid & (QB - 1);
    float cx = cxs[q], cy = cys[q];

    // phase 1: QB*400 = 3200 dots; idx = p*8 + q (8 lanes share one t-row address)
    for (int it = 0; it < 13; ++it) {
        int idx = tid + it * 256;
        if (idx < QB * 400) {
            int p = idx >> 3;                 // 0..399
            int lvl = p / 100, rem = p % 100;
            int u = rem / 10, v = rem % 10;
            float scale = 1.0f / (float)(1 << lvl);
            float cxl = cx * scale, cyl = cy * scale;
            int X0 = (int)floorf(cxl), Y0 = (int)floorf(cyl);
            int wl = 64 >> lvl;
            int xi = X0 - 4 + u, yi = Y0 - 4 + v;
            float r = 0.f;
            if (xi >= 0 && xi < wl && yi >= 0 && yi < wl) {
                const uint4* tv = (const uint4*)(t + c_toff[lvl] + (((size_t)b * wl + yi) * (size_t)wl + xi) * DIM);
#if HAVE_DOT2
                float a0 = 0.f, a1 = 0.f, a2 = 0.f, a3 = 0.f;
#pragma unroll
                for (int k = 0; k < 32; ++k) {
                    uint4 wv = tv[k];
                    uint4 gv = *(const uint4*)&gu[q][k * 4];
                    a0 = dot2bf(wv.x, gv.x, a0);
                    a1 = dot2bf(wv.y, gv.y, a1);
                    a2 = dot2bf(wv.z, gv.z, a2);
                    a3 = dot2bf(wv.w, gv.w, a3);
                }
                r = (a0 + a1) + (a2 + a3);
#else
                float a0 = 0.f, a1 = 0.f, a2 = 0.f, a3 = 0.f, a4 = 0.f, a5 = 0.f, a6 = 0.f, a7 = 0.f;
#pragma unroll
                for (int k = 0; k < 32; ++k) {
                    uint4 wv = tv[k];
                    float4 ga = *(const float4*)&gf[q][k * 8];
                    float4 gb = *(const float4*)&gf[q][k * 8 + 4];
                    a0 += bflo(wv.x) * ga.x;  a1 += bfhi(wv.x) * ga.y;
                    a2 += bflo(wv.y) * ga.z;  a3 += bfhi(wv.y) * ga.w;
                    a4 += bflo(wv.z) * gb.x;  a5 += bfhi(wv.z) * gb.y;
                    a6 += bflo(wv.w) * gb.z;  a7 += bfhi(wv.w) * gb.w;
                }
                r = ((a0 + a1) + (a2 + a3)) + ((a4 + a5) + (a6 + a7));
#endif
            }
            Dl[q][p] = r;
        }
    }
    __syncthreads();

    // phase 2: QB*324 outputs; idx = ch*8 + q
    for (int idx = tid; idx < QB * NCH; idx += 256) {
        int ch = idx >> 3, qq = idx & (QB - 1);
        int lvl = ch / 81, rem2 = ch % 81;
        int a = rem2 / 9, bb = rem2 % 9;
        float cx2 = cxs[qq], cy2 = cys[qq];
        float scale = 1.0f / (float)(1 << lvl);
        float cxl = cx2 * scale, cyl = cy2 * scale;
        float fx = cxl - floorf(cxl), fy = cyl - floorf(cyl);
        float wx0 = 1.f - fx, wy0 = 1.f - fy;
        int base = lvl * 100 + a * 10 + bb;
        float v00 = Dl[qq][base],     v10 = Dl[qq][base + 10];
        float v01 = Dl[qq][base + 1], v11 = Dl[qq][base + 11];
        float val = wy0 * (wx0 * v00 + fx * v10) + fy * (wx0 * v01 + fx * v11);
        out[(((size_t)b * NCH + ch) * HH + y) * WW + (x0 + qq)] = val;
    }
}

extern "C" void kernel_launch(void* const* d_in, const int* in_sizes, int n_in,
                              void* d_out, int out_size, void* d_ws, size_t ws_size,
                              hipStream_t stream) {
    const float* f1     = (const float*)d_in[0];
    const float* f2     = (const float*)d_in[1];
    const float* coords = (const float*)d_in[2];
    const float* rp     = (const float*)d_in[3];
    const float* rd     = (const float*)d_in[4];
    float* out = (float*)d_out;

    // workspace carve (floats)
    float* S    = (float*)d_ws;
    float* M2   = S   + 65536;
    float* M4   = M2  + 65536;
    float* Um   = M4  + 65536;
    float* Pm   = Um  + 65536;
    float* Wms  = Pm  + 65536;
    float* dvec = Wms + 65536;                               // 256 floats
    unsigned short* g1 = (unsigned short*)(dvec + 256);      // 2*4096*256 bf16
    unsigned short* t  = g1 + (size_t)NB * HW * DIM;         // 2785280 bf16

    prep_kernel<<<256, 256, 0, stream>>>(rp, rd, S, dvec);
    gemm_plain<<<256, 256, 0, stream>>>(S,  S,  M2);     // S^2
    gemm_plain<<<256, 256, 0, stream>>>(M2, M2, M4);     // S^4
    gemm_U    <<<256, 256, 0, stream>>>(S,  M2, Um);     // (I+S)^2 (I+S^2)
    gemm_P    <<<256, 256, 0, stream>>>(Um, M4, Pm);     // * (I+S^4) = P
    gemmW_kernel<<<256, 256, 0, stream>>>(Pm, dvec, Wms);

    g1_kernel<<<dim3(64, 2, 2), 256, 0, stream>>>(f1, Wms, (unsigned int*)g1);
    pool_kernel<<<dim3(120, 2), 256, 0, stream>>>(f2, t);
    sample_kernel<<<NQ / QB, 256, 0, stream>>>(g1, t, coords, out);
}

// Round 9
// 358.404 us; speedup vs baseline: 2.0179x; 1.2992x over previous
//
#include <hip/hip_runtime.h>
#include <hip/hip_bf16.h>
#include <stdint.h>

// LearnableCorrBlock: fmap1/2 [2,256,64,64] f32, coords [2,2,64,64], raw_P [256,256], raw_D [256]
// out [2, 4*81, 64, 64] f32.
//
//  - W-chain: P = (I+S)^2 (I+S^2)(I+S^4)  (Neumann, err ~||S||^8 ~ 4e-7); Wms = P^T D P /16
//  - g1[b,i,c] = f1^T Wms (bf16), coalesced via LDS transpose (512 blocks, 2/CU)
//  - t_l[b,y,x,c] = pooled fmap2, bf16; coalesced read + LDS transpose write
//  - sampler: QB=4 queries/block (grid 2048 = 8 blocks/CU for occupancy), p-major dot
//    ordering (4-way load merge), packed-bf16 LDS + v_dot2, 8 chains x 16-deep.
//    NOTE: no min-waves launch_bounds hint — (256,4) forced 64 VGPRs and ~217MB/dispatch
//    of scratch spill traffic (round 5: WRITE_SIZE 228MB vs 10.6MB ideal).
//    Round 8: QB=8 grid 1024 was grid-limited to 35% occupancy, VALUBusy 9% -> latency-bound.

#define DIM 256
#define HH 64
#define WW 64
#define HW 4096
#define NB 2
#define NQ 8192
#define NCH 324
#define QB 4

__device__ __constant__ size_t c_toff[4] = {0, 2097152, 2621440, 2752512};

static __device__ __forceinline__ unsigned short f2bf(float f) {
    unsigned int u = __float_as_uint(f);
    unsigned int r = (u + 0x7fffu + ((u >> 16) & 1u)) >> 16;   // RNE
    return (unsigned short)r;
}
static __device__ __forceinline__ float bflo(unsigned int u) { return __uint_as_float(u << 16); }
static __device__ __forceinline__ float bfhi(unsigned int u) { return __uint_as_float(u & 0xffff0000u); }

#if __has_builtin(__builtin_amdgcn_fdot2_f32_bf16)
typedef __bf16 bf16x2_t __attribute__((ext_vector_type(2)));
#define HAVE_DOT2 1
static __device__ __forceinline__ float dot2bf(unsigned int a, unsigned int b, float c) {
    return __builtin_amdgcn_fdot2_f32_bf16(__builtin_bit_cast(bf16x2_t, a),
                                           __builtin_bit_cast(bf16x2_t, b), c, false);
}
#else
#define HAVE_DOT2 0
#endif

// ---------- 1. prep: skew S and diagonal dvec ----------
__global__ void prep_kernel(const float* __restrict__ rp, const float* __restrict__ rd,
                            float* __restrict__ S, float* __restrict__ dvec) {
    int i = blockIdx.x, j = threadIdx.x;
    float v = 0.f;
    if (j > i)      v =  0.5f * rp[i * DIM + j];
    else if (j < i) v = -0.5f * rp[j * DIM + i];
    S[i * DIM + j] = v;
    if (i == 0) {
        float t = atanf(rd[j]) * 0.63661977236758134f;  // 2/pi
        dvec[j] = (1.0f + t) / (1.0f - t);
    }
}

// ---------- 2. row-per-block GEMMs (A-row uniform -> s_loads; B coalesced) ----------
__global__ __launch_bounds__(256) void gemm_plain(const float* __restrict__ A,
                                                  const float* __restrict__ B,
                                                  float* __restrict__ C) {
    int i = blockIdx.x, j = threadIdx.x;
    const float* a = A + (size_t)i * DIM;
    float acc = 0.f;
#pragma unroll 8
    for (int k = 0; k < DIM; ++k) acc += a[k] * B[k * DIM + j];
    C[i * DIM + j] = acc;
}

// U = (I + 2S + M2) @ (I + M2)
__global__ __launch_bounds__(256) void gemm_U(const float* __restrict__ S,
                                              const float* __restrict__ M2,
                                              float* __restrict__ U) {
    int i = blockIdx.x, j = threadIdx.x;
    const float* s = S + (size_t)i * DIM;
    const float* m = M2 + (size_t)i * DIM;
    float acc = 0.f;
#pragma unroll 8
    for (int k = 0; k < DIM; ++k) {
        float av = 2.f * s[k] + m[k] + ((k == i) ? 1.f : 0.f);
        acc += av * M2[k * DIM + j];
    }
    acc += 2.f * s[j] + m[j] + ((j == i) ? 1.f : 0.f);
    U[i * DIM + j] = acc;
}

// P = U @ (I + M4)
__global__ __launch_bounds__(256) void gemm_P(const float* __restrict__ U,
                                              const float* __restrict__ M4,
                                              float* __restrict__ P) {
    int i = blockIdx.x, j = threadIdx.x;
    const float* a = U + (size_t)i * DIM;
    float acc = 0.f;
#pragma unroll 8
    for (int k = 0; k < DIM; ++k) acc += a[k] * M4[k * DIM + j];
    acc += a[j];
    P[i * DIM + j] = acc;
}

// ---------- 3. Wms[i,j] = sum_k P[k,i]*d[k]*P[k,j] / 16 (LDS-staged column) ----------
__global__ __launch_bounds__(256) void gemmW_kernel(const float* __restrict__ P,
                                                    const float* __restrict__ dvec,
                                                    float* __restrict__ Wms) {
    __shared__ float col[DIM];
    int i = blockIdx.x, j = threadIdx.x;
    col[j] = P[j * DIM + i] * dvec[j];
    __syncthreads();
    float acc = 0.f;
#pragma unroll 8
    for (int k = 0; k < DIM; ++k) acc += col[k] * P[k * DIM + j];
    Wms[i * DIM + j] = acc * 0.0625f;
}

// ---------- 4. g1[b,i,c] = sum_c' f1[b,c',i] * Wms[c',c]  (bf16, coalesced store) ----------
// grid dim3(64, 4, 2): i-tile 64, c-tile 64 -> 512 blocks (2/CU, 8 waves/CU)
__global__ __launch_bounds__(256) void g1_kernel(const float* __restrict__ f1,
                                                 const float* __restrict__ Wms,
                                                 unsigned int* __restrict__ g1u) {
    __shared__ unsigned int lt[64][33];
    int b = blockIdx.z;
    int tid = threadIdx.x;
    int il = tid & 63, w = tid >> 6;
    int i = blockIdx.x * 64 + il;
    int cb = blockIdx.y * 64 + w * 16;      // wave-uniform
    const float* f1p = f1 + (size_t)b * DIM * HW + i;
    float acc[16];
#pragma unroll
    for (int c = 0; c < 16; ++c) acc[c] = 0.f;
    for (int cp = 0; cp < DIM; ++cp) {
        float a = f1p[(size_t)cp * HW];
        const float* wrow = Wms + cp * DIM + cb;  // wave-uniform -> scalar loads
#pragma unroll
        for (int c = 0; c < 16; ++c) acc[c] += a * wrow[c];
    }
#pragma unroll
    for (int m = 0; m < 8; ++m) {
        unsigned int u = (unsigned int)f2bf(acc[2 * m]) | ((unsigned int)f2bf(acc[2 * m + 1]) << 16);
        lt[il][w * 8 + m] = u;
    }
    __syncthreads();
    unsigned int* dst = g1u + ((size_t)b * HW + blockIdx.x * 64) * 128 + blockIdx.y * 32;
#pragma unroll
    for (int j2 = 0; j2 < 8; ++j2) {
        int idx = tid + 256 * j2;
        int row = idx >> 5, cu = idx & 31;
        dst[(size_t)row * 128 + cu] = lt[row][cu];
    }
}

// ---------- 5. pooled + transposed f2 -> t_l[b,y,x,c] bf16 (coalesced both sides) ----------
__global__ __launch_bounds__(256) void pool_kernel(const float* __restrict__ f2,
                                                   unsigned short* __restrict__ t) {
    __shared__ unsigned short tile[64][258];   // 258 stride: bank = (xl + c/2)%32, 2-way max
    int b = blockIdx.y;
    int r = blockIdx.x;
    int lvl, y;
    if (r < 64)       { lvl = 0; y = r; }
    else if (r < 96)  { lvl = 1; y = r - 64; }
    else if (r < 112) { lvl = 2; y = r - 96; }
    else              { lvl = 3; y = r - 112; }
    int wl = 64 >> lvl;            // 64,32,16,8
    int s = 1 << lvl;
    int shift = 6 - lvl;           // log2(wl)
    int ncg = 4 << lvl;            // 256/wl
    float inv = 1.0f / (float)(s * s);
    int tid = threadIdx.x;
    int xl = tid & (wl - 1);
    int cg = tid >> shift;

    for (int c = cg; c < DIM; c += ncg) {
        const float* src = f2 + (((size_t)b * DIM + c) * HH + y * s) * WW + xl * s;
        float acc = 0.f;
        for (int dy = 0; dy < s; ++dy) {
            const float* rowp = src + dy * WW;
            if (s == 1)      acc += rowp[0];
            else if (s == 2) { float2 v = *(const float2*)rowp; acc += v.x + v.y; }
            else if (s == 4) { float4 v = *(const float4*)rowp; acc += v.x + v.y + v.z + v.w; }
            else             { float4 v0 = *(const float4*)rowp; float4 v1 = *(const float4*)(rowp + 4);
                               acc += (v0.x + v0.y + v0.z + v0.w) + (v1.x + v1.y + v1.z + v1.w); }
        }
        tile[xl][c] = f2bf(acc * inv);
    }
    __syncthreads();
    unsigned short* dstbase = t + c_toff[lvl] + (((size_t)b * wl + y) * (size_t)wl) * DIM;
    int cu = tid & 127, xr = tid >> 7;
    for (int p0 = 0; p0 < wl; p0 += 2) {
        int xw = p0 + xr;
        unsigned int val = (unsigned int)tile[xw][2 * cu] | ((unsigned int)tile[xw][2 * cu + 1] << 16);
        *(unsigned int*)(dstbase + (size_t)xw * DIM + 2 * cu) = val;
    }
}

// ---------- 6. sampler v4: QB=4, grid 2048, p-major, packed-bf16 LDS + dot2, 8 chains ----------
__global__ __launch_bounds__(256) void sample_kernel(const unsigned short* __restrict__ g1,
                                                     const unsigned short* __restrict__ t,
                                                     const float* __restrict__ coords,
                                                     float* __restrict__ out) {
#if HAVE_DOT2
    __shared__ __align__(16) unsigned int gu[QB][132];
#else
    __shared__ __align__(16) float gf[QB][260];
#endif
    __shared__ float Dl[QB][401];
    __shared__ float cxs[QB], cys[QB];

    int bid = blockIdx.x;
    int swz = (bid & 7) * 256 + (bid >> 3);   // bijective XCD swizzle, 2048 blocks
    int qbase = swz * QB;
    int b = qbase >> 12, y = (qbase >> 6) & 63, x0 = qbase & 63;
    int tid = threadIdx.x;

    if (tid < QB * 32) {   // QB g1 rows = QB*256 bf16 = QB*32 uint4
        const uint4* src = (const uint4*)(g1 + (size_t)qbase * DIM);
        uint4 wv = src[tid];
#if HAVE_DOT2
        *(uint4*)&gu[tid >> 5][(tid & 31) * 4] = wv;
#else
        float* dst = &gf[tid >> 5][(tid & 31) * 8];
        dst[0] = bflo(wv.x); dst[1] = bfhi(wv.x);
        dst[2] = bflo(wv.y); dst[3] = bfhi(wv.y);
        dst[4] = bflo(wv.z); dst[5] = bfhi(wv.z);
        dst[6] = bflo(wv.w); dst[7] = bfhi(wv.w);
#endif
    }
    if (tid < QB) {
        cxs[tid] = coords[(((size_t)b * 2 + 0) * HH + y) * WW + (x0 + tid)];
        cys[tid] = coords[(((size_t)b * 2 + 1) * HH + y) * WW + (x0 + tid)];
    }
    __syncthreads();

    int q = tid & (QB - 1);
    float cx = cxs[q], cy = cys[q];

    // phase 1: QB*400 = 1600 dots; idx = p*QB + q (QB lanes share one t-row address)
    for (int it = 0; it < 7; ++it) {
        int idx = tid + it * 256;
        if (idx < QB * 400) {
            int p = idx >> 2;                 // 0..399
            int lvl = p / 100, rem = p % 100;
            int u = rem / 10, v = rem % 10;
            float scale = 1.0f / (float)(1 << lvl);
            float cxl = cx * scale, cyl = cy * scale;
            int X0 = (int)floorf(cxl), Y0 = (int)floorf(cyl);
            int wl = 64 >> lvl;
            int xi = X0 - 4 + u, yi = Y0 - 4 + v;
            float r = 0.f;
            if (xi >= 0 && xi < wl && yi >= 0 && yi < wl) {
                const uint4* tv = (const uint4*)(t + c_toff[lvl] + (((size_t)b * wl + yi) * (size_t)wl + xi) * DIM);
#if HAVE_DOT2
                float a0 = 0.f, a1 = 0.f, a2 = 0.f, a3 = 0.f, a4 = 0.f, a5 = 0.f, a6 = 0.f, a7 = 0.f;
#pragma unroll
                for (int k = 0; k < 32; k += 2) {
                    uint4 w0 = tv[k],     g0 = *(const uint4*)&gu[q][k * 4];
                    uint4 w1 = tv[k + 1], g1v = *(const uint4*)&gu[q][k * 4 + 4];
                    a0 = dot2bf(w0.x, g0.x, a0);  a1 = dot2bf(w0.y, g0.y, a1);
                    a2 = dot2bf(w0.z, g0.z, a2);  a3 = dot2bf(w0.w, g0.w, a3);
                    a4 = dot2bf(w1.x, g1v.x, a4); a5 = dot2bf(w1.y, g1v.y, a5);
                    a6 = dot2bf(w1.z, g1v.z, a6); a7 = dot2bf(w1.w, g1v.w, a7);
                }
                r = ((a0 + a1) + (a2 + a3)) + ((a4 + a5) + (a6 + a7));
#else
                float a0 = 0.f, a1 = 0.f, a2 = 0.f, a3 = 0.f, a4 = 0.f, a5 = 0.f, a6 = 0.f, a7 = 0.f;
#pragma unroll
                for (int k = 0; k < 32; ++k) {
                    uint4 wv = tv[k];
                    float4 ga = *(const float4*)&gf[q][k * 8];
                    float4 gb = *(const float4*)&gf[q][k * 8 + 4];
                    a0 += bflo(wv.x) * ga.x;  a1 += bfhi(wv.x) * ga.y;
                    a2 += bflo(wv.y) * ga.z;  a3 += bfhi(wv.y) * ga.w;
                    a4 += bflo(wv.z) * gb.x;  a5 += bfhi(wv.z) * gb.y;
                    a6 += bflo(wv.w) * gb.z;  a7 += bfhi(wv.w) * gb.w;
                }
                r = ((a0 + a1) + (a2 + a3)) + ((a4 + a5) + (a6 + a7));
#endif
            }
            Dl[q][p] = r;
        }
    }
    __syncthreads();

    // phase 2: QB*324 outputs; idx = ch*QB + q
    for (int idx = tid; idx < QB * NCH; idx += 256) {
        int ch = idx >> 2, qq = idx & (QB - 1);
        int lvl = ch / 81, rem2 = ch % 81;
        int a = rem2 / 9, bb = rem2 % 9;
        float cx2 = cxs[qq], cy2 = cys[qq];
        float scale = 1.0f / (float)(1 << lvl);
        float cxl = cx2 * scale, cyl = cy2 * scale;
        float fx = cxl - floorf(cxl), fy = cyl - floorf(cyl);
        float wx0 = 1.f - fx, wy0 = 1.f - fy;
        int base = lvl * 100 + a * 10 + bb;
        float v00 = Dl[qq][base],     v10 = Dl[qq][base + 10];
        float v01 = Dl[qq][base + 1], v11 = Dl[qq][base + 11];
        float val = wy0 * (wx0 * v00 + fx * v10) + fy * (wx0 * v01 + fx * v11);
        out[(((size_t)b * NCH + ch) * HH + y) * WW + (x0 + qq)] = val;
    }
}

extern "C" void kernel_launch(void* const* d_in, const int* in_sizes, int n_in,
                              void* d_out, int out_size, void* d_ws, size_t ws_size,
                              hipStream_t stream) {
    const float* f1     = (const float*)d_in[0];
    const float* f2     = (const float*)d_in[1];
    const float* coords = (const float*)d_in[2];
    const float* rp     = (const float*)d_in[3];
    const float* rd     = (const float*)d_in[4];
    float* out = (float*)d_out;

    // workspace carve (floats)
    float* S    = (float*)d_ws;
    float* M2   = S   + 65536;
    float* M4   = M2  + 65536;
    float* Um   = M4  + 65536;
    float* Pm   = Um  + 65536;
    float* Wms  = Pm  + 65536;
    float* dvec = Wms + 65536;                               // 256 floats
    unsigned short* g1 = (unsigned short*)(dvec + 256);      // 2*4096*256 bf16
    unsigned short* t  = g1 + (size_t)NB * HW * DIM;         // 2785280 bf16

    prep_kernel<<<256, 256, 0, stream>>>(rp, rd, S, dvec);
    gemm_plain<<<256, 256, 0, stream>>>(S,  S,  M2);     // S^2
    gemm_plain<<<256, 256, 0, stream>>>(M2, M2, M4);     // S^4
    gemm_U    <<<256, 256, 0, stream>>>(S,  M2, Um);     // (I+S)^2 (I+S^2)
    gemm_P    <<<256, 256, 0, stream>>>(Um, M4, Pm);     // * (I+S^4) = P
    gemmW_kernel<<<256, 256, 0, stream>>>(Pm, dvec, Wms);

    g1_kernel<<<dim3(64, 4, 2), 256, 0, stream>>>(f1, Wms, (unsigned int*)g1);
    pool_kernel<<<dim3(120, 2), 256, 0, stream>>>(f2, t);
    sample_kernel<<<NQ / QB, 256, 0, stream>>>(g1, t, coords, out);
}